// Round 9
// baseline (185.248 us; speedup 1.0000x reference)
//
#include <hip/hip_runtime.h>

// MultiScaleRoIAlign: B=2, Nb=256 (R=512 rois), C=256, PH=PW=7, GRID=2.
// R13 = R12 with the macro-comment compile error fixed (a '//' line inside
// the COMPUTE macro lacked a continuation backslash and truncated the macro).
// R12 theory: SQ_LDS_BANK_CONFLICT byte-identical (1922752) across
// R6/R8/R9/R11 -> DS pressure is in the COMPUTE phase all four shared:
// 8 __shfl_xor lower to ds_swizzle (32 DS wave-instrs/block-round) and the
// reduce is a ds_read->fmac->swizzle->add->swizzle->add dependent chain
// ping-ponging DS<->VALU (both ~30%, serialized). Changes vs R11:
//   - quad reduce via DPP quad_perm (mov_dpp 0xB1/0x4E + v_add): pure VALU,
//     0 DS instrs. Quads uniformly active (bin = tid>>2) -> DPP safe.
//   - gsrc[k] arithmetic guarded by k < smax (dead-VALU cut; pure ALU, no
//     R8-style load-serialization risk).
// Staging identical to R11 (verified): DMA global_load_lds, pre-swizzled
// source, channel-interleaved float4 slab, double-buffered, 1 barrier/round.

#define PHW 49
#define NCHUNK 8
#define CH 32             // channels per block (8 rounds of 4)
#define SLABQ 960         // float4 per slab (3840 floats = 15360 B)

__device__ __forceinline__ float quad_xor1_add(float x) {
    const int y = __builtin_amdgcn_mov_dpp(__float_as_int(x),
                                           0xB1, 0xF, 0xF, true);
    return x + __int_as_float(y);      // quad_perm [1,0,3,2]
}
__device__ __forceinline__ float quad_xor2_add(float x) {
    const int y = __builtin_amdgcn_mov_dpp(__float_as_int(x),
                                           0x4E, 0xF, 0xF, true);
    return x + __int_as_float(y);      // quad_perm [2,3,0,1]
}

__global__ __launch_bounds__(256) void msroi_kernel(
    const float* __restrict__ f0, const float* __restrict__ f1,
    const float* __restrict__ f2, const float* __restrict__ f3,
    const float* __restrict__ boxes, float* __restrict__ out)
{
    const int C = 256, Nb = 256;
    const int r = blockIdx.x;            // roi 0..511
    const int chunk = blockIdx.y;        // 0..7
    const int tid = threadIdx.x;         // 0..255
    const int b = r / Nb;

    const int bin = tid >> 2;            // 0..63 (active if < 49)
    const int q   = tid & 3;             // 2x2 sample index within bin
    const bool active = bin < PHW;       // uniform per quad -> DPP-safe

    // ---- per-roi params (uniform) ----
    const float x1b = boxes[r * 4 + 0];
    const float y1b = boxes[r * 4 + 1];
    const float x2b = boxes[r * 4 + 2];
    const float y2b = boxes[r * 4 + 3];
    const float area = fmaxf((x2b - x1b) * (y2b - y1b), 0.0f);
    const float s = sqrtf(area);
    float lv = floorf(4.0f + log2f(s / 224.0f + 1e-6f));
    lv = fminf(fmaxf(lv, 2.0f), 5.0f);
    const int lvl = (int)lv - 2;

    const float* feat;
    int H, W;
    float scale;
    switch (lvl) {
        case 0:  feat = f0; H = 200; W = 200; scale = 0.25f;    break;
        case 1:  feat = f1; H = 100; W = 100; scale = 0.125f;   break;
        case 2:  feat = f2; H = 50;  W = 50;  scale = 0.0625f;  break;
        default: feat = f3; H = 25;  W = 25;  scale = 0.03125f; break;
    }
    const int HW = H * W;

    const float x1 = x1b * scale, y1 = y1b * scale;
    const float x2 = x2b * scale, y2 = y2b * scale;
    const float roi_w = fmaxf(x2 - x1, 1.0f);
    const float roi_h = fmaxf(y2 - y1, 1.0f);
    const float bin_w = roi_w * (1.0f / 7.0f);
    const float bin_h = roi_h * (1.0f / 7.0f);

    // ---- patch bounds (uniform) ----
    const float ys0 = fminf(fmaxf(y1 + 0.25f * bin_h, 0.0f), (float)(H - 1));
    const float ys1 = fminf(fmaxf(y1 + 6.75f * bin_h, 0.0f), (float)(H - 1));
    const float xs0 = fminf(fmaxf(x1 + 0.25f * bin_w, 0.0f), (float)(W - 1));
    const float xs1 = fminf(fmaxf(x1 + 6.75f * bin_w, 0.0f), (float)(W - 1));
    const int row0 = (int)floorf(ys0);
    const int row1 = min((int)floorf(ys1) + 1, H - 1);
    const int col0 = (int)floorf(xs0);
    const int col1 = min((int)floorf(xs1) + 1, W - 1);
    const int prows = row1 - row0 + 1;
    const int pcols = col1 - col0 + 1;
    const int psize = prows * pcols;
    const int wstride = W - pcols;                 // row jump in global plane
    const float inv_pcols = 1.0f / (float)pcols;

    // ---- per-lane DMA source offsets (loop-invariant, byte offsets) ----
    // slot s = k*256 + tid of the interleaved slab; elem e = s>>2, ch = s&3.
    const int smax = (psize + 63) >> 6;            // <= 15, block-uniform
    int gsrc[15];
#pragma unroll
    for (int k = 0; k < 15; ++k) {
        if (k < smax) {
            const int sl = k * 256 + tid;
            const int sc = min(sl, 4 * psize - 1);
            const int e  = sc >> 2;
            const int cl = sc & 3;
            const int rr = (int)floorf(((float)e + 0.5f) * inv_pcols);
            gsrc[k] = (cl * HW + e + rr * wstride) * 4;
        } else {
            gsrc[k] = 0;
        }
    }

    // ---- per-lane tap descriptors: sample q of bin -> 4 bilinear taps ----
    int   offs[4];
    float wts[4];
    {
        const int bb = active ? bin : 0;
        const int ph = bb / 7;
        const int pw = bb - ph * 7;
        const int iy = q >> 1, ix = q & 1;
        const float gy = (float)ph + ((float)iy + 0.5f) * 0.5f;
        const float gx = (float)pw + ((float)ix + 0.5f) * 0.5f;
        const float y = y1 + gy * bin_h;
        const float x = x1 + gx * bin_w;
        const bool valid = (y >= -1.0f) && (y <= (float)H) &&
                           (x >= -1.0f) && (x <= (float)W);
        const float yc = fminf(fmaxf(y, 0.0f), (float)(H - 1));
        const float xc = fminf(fmaxf(x, 0.0f), (float)(W - 1));
        const int yl = (int)floorf(yc);
        const int xl = (int)floorf(xc);
        const int yh = min(yl + 1, H - 1);
        const int xh = min(xl + 1, W - 1);
        const float ly = yc - (float)yl;
        const float lx = xc - (float)xl;
        const float hy = 1.0f - ly, hx = 1.0f - lx;
        const float m = valid ? 0.25f : 0.0f;
        const int ry0 = (yl - row0) * pcols, ry1 = (yh - row0) * pcols;
        const int cx0 = xl - col0, cx1 = xh - col0;
        offs[0] = ry0 + cx0;  wts[0] = hy * hx * m;
        offs[1] = ry0 + cx1;  wts[1] = hy * lx * m;
        offs[2] = ry1 + cx0;  wts[2] = ly * hx * m;
        offs[3] = ry1 + cx1;  wts[3] = ly * lx * m;
    }

    // ---- double-buffered interleaved slabs: lds4[s][e] = {c0..c3}[e] ----
    __shared__ float4 lds4[2][SLABQ];    // 30720 B -> 5 blocks/CU

    const int cbase = chunk * CH;
    const float* __restrict__ fch =
        feat + (size_t)(b * C + cbase) * HW + (row0 * W + col0);
    float* __restrict__ outp =
        out + (size_t)r * C * PHW + (size_t)cbase * PHW;

    const int wbase4 = (tid & 192) * 4;  // wave LDS byte base within a batch

    // DMA: dest = wave-uniform base + lane*4 (linear); per-lane global src.
#define STAGE(SL, CC)                                                      \
    do {                                                                   \
        const char* gb = (const char*)fch + (size_t)(CC) * HW * 4;         \
        char* lb = (char*)(&lds4[SL][0]);                                  \
        _Pragma("unroll")                                                  \
        for (int k = 0; k < 15; ++k) {                                     \
            if (k < smax) {                                                \
                __builtin_amdgcn_global_load_lds(                          \
                    (const __attribute__((address_space(1))) void*)        \
                        (gb + gsrc[k]),                                    \
                    (__attribute__((address_space(3))) void*)              \
                        (lb + k * 1024 + wbase4),                          \
                    4, 0, 0);                                              \
            }                                                              \
        }                                                                  \
    } while (0)

#define COMPUTE(SL, CCV)                                                   \
    do {                                                                   \
        if (active) {                                                      \
            float4 a = make_float4(0.0f, 0.0f, 0.0f, 0.0f);                \
            _Pragma("unroll")                                              \
            for (int j = 0; j < 4; ++j) {                                  \
                const float4 v = lds4[SL][offs[j]];                        \
                a.x += wts[j] * v.x;                                       \
                a.y += wts[j] * v.y;                                       \
                a.z += wts[j] * v.z;                                       \
                a.w += wts[j] * v.w;                                       \
            }                                                              \
            a.x = quad_xor1_add(a.x); a.y = quad_xor1_add(a.y);            \
            a.z = quad_xor1_add(a.z); a.w = quad_xor1_add(a.w);            \
            a.x = quad_xor2_add(a.x); a.y = quad_xor2_add(a.y);            \
            a.z = quad_xor2_add(a.z); a.w = quad_xor2_add(a.w);            \
            const float vout = (q == 0) ? a.x : (q == 1) ? a.y             \
                             : (q == 2) ? a.z : a.w;                       \
            outp[(size_t)((CCV) + q) * PHW + bin] = vout;                  \
        }                                                                  \
    } while (0)

    // Prologue: DMA slab0 (channels 0..3), drain, publish.
    STAGE(0, 0);
    __syncthreads();                     // vmcnt(0)+lgkmcnt(0)+barrier

    // Segment i: issue DMA for slab nxt (overlaps compute), compute cur,
    // drain + barrier. WAR safe: COMPUTE(i)'s reads of slab cur are
    // data-consumed before barrier(i); STAGE into cur only at i+1.
#pragma unroll
    for (int i = 0; i < 8; ++i) {
        const int cur = i & 1;
        if (i < 7) STAGE(cur ^ 1, (i + 1) * 4);
        COMPUTE(cur, i * 4);
        __syncthreads();                 // drains this segment's DMA too
    }
#undef STAGE
#undef COMPUTE
}

extern "C" void kernel_launch(void* const* d_in, const int* in_sizes, int n_in,
                              void* d_out, int out_size, void* d_ws, size_t ws_size,
                              hipStream_t stream) {
    const float* f0 = (const float*)d_in[0];
    const float* f1 = (const float*)d_in[1];
    const float* f2 = (const float*)d_in[2];
    const float* f3 = (const float*)d_in[3];
    const float* boxes = (const float*)d_in[4];
    float* out = (float*)d_out;

    const int R = in_sizes[4] / 4;   // 512 rois
    dim3 grid(R, NCHUNK);
    msroi_kernel<<<grid, 256, 0, stream>>>(f0, f1, f2, f3, boxes, out);
}

// Round 10
// 178.805 us; speedup vs baseline: 1.0360x; 1.0360x over previous
//
#include <hip/hip_runtime.h>

// MultiScaleRoIAlign: B=2, Nb=256 (R=512 rois), C=256, PH=PW=7, GRID=2.
// R14: delete the lockstep. Six schedule variants (R4..R13) all land at
// 69-77us because every one shares barrier-locked rounds: ~65k cy/CU of
// idle from 2 barriers/round around ~400cy dependency chains, only ~3
// blocks/CU overlapping. This kernel has ZERO barriers:
//   - wave-private double-buffered single-channel patch slab (896 floats;
//     tight psize bound: feat-space roi < 98x28 -> psize < 878)
//   - per wave: 8 channels serially; per channel: wave-local
//     s_waitcnt vmcnt(0) (1 full pass of slack) -> DMA-stage next channel
//     -> compute -> coalesced store. Waves free-run; pipes interleave.
//   - compute: lane=bin (49/64 active), 8 paired LDS reads (x-taps adjacent
//     -> ds_read2_b32; xh==xl edge has lx=0 so +1 slot's garbage is
//     weight-zero; staged through slot psize so it is always finite)
//   - staging: global_load_lds DMA (no dest regs -> dynamic smax loop is
//     safe from R8-style serialization), smax=(psize>>6)+1 covers psize+1.
// LDS 4 waves x 2 x 3584B = 28.7KB -> 5 blocks/CU = 20 waves, no sync.

#define PHW 49
#define NCHUNK 8
#define SLABN 896         // floats per slab (= 14 * 64)
#define SMAXN 14

__global__ __launch_bounds__(256) void msroi_kernel(
    const float* __restrict__ f0, const float* __restrict__ f1,
    const float* __restrict__ f2, const float* __restrict__ f3,
    const float* __restrict__ boxes, float* __restrict__ out)
{
    const int C = 256, Nb = 256;
    const int r = blockIdx.x;            // roi 0..511
    const int chunk = blockIdx.y;        // 0..7
    const int tid = threadIdx.x;         // 0..255
    const int w = tid >> 6;              // wave 0..3 (private slab owner)
    const int lane = tid & 63;
    const int b = r / Nb;

    const int bin = lane;                // lanes >= 49 idle in compute
    const bool active = bin < PHW;

    // ---- per-roi params (uniform) ----
    const float x1b = boxes[r * 4 + 0];
    const float y1b = boxes[r * 4 + 1];
    const float x2b = boxes[r * 4 + 2];
    const float y2b = boxes[r * 4 + 3];
    const float area = fmaxf((x2b - x1b) * (y2b - y1b), 0.0f);
    const float s = sqrtf(area);
    float lv = floorf(4.0f + log2f(s / 224.0f + 1e-6f));
    lv = fminf(fmaxf(lv, 2.0f), 5.0f);
    const int lvl = (int)lv - 2;

    const float* feat;
    int H, W;
    float scale;
    switch (lvl) {
        case 0:  feat = f0; H = 200; W = 200; scale = 0.25f;    break;
        case 1:  feat = f1; H = 100; W = 100; scale = 0.125f;   break;
        case 2:  feat = f2; H = 50;  W = 50;  scale = 0.0625f;  break;
        default: feat = f3; H = 25;  W = 25;  scale = 0.03125f; break;
    }
    const int HW = H * W;

    const float x1 = x1b * scale, y1 = y1b * scale;
    const float x2 = x2b * scale, y2 = y2b * scale;
    const float roi_w = fmaxf(x2 - x1, 1.0f);
    const float roi_h = fmaxf(y2 - y1, 1.0f);
    const float bin_w = roi_w * (1.0f / 7.0f);
    const float bin_h = roi_h * (1.0f / 7.0f);

    // ---- patch bounds (uniform): samples at gy,gx in {0.25 .. 6.75} ----
    const float ys0 = fminf(fmaxf(y1 + 0.25f * bin_h, 0.0f), (float)(H - 1));
    const float ys1 = fminf(fmaxf(y1 + 6.75f * bin_h, 0.0f), (float)(H - 1));
    const float xs0 = fminf(fmaxf(x1 + 0.25f * bin_w, 0.0f), (float)(W - 1));
    const float xs1 = fminf(fmaxf(x1 + 6.75f * bin_w, 0.0f), (float)(W - 1));
    const int row0 = (int)floorf(ys0);
    const int row1 = min((int)floorf(ys1) + 1, H - 1);
    const int col0 = (int)floorf(xs0);
    const int col1 = min((int)floorf(xs1) + 1, W - 1);
    const int prows = row1 - row0 + 1;
    const int pcols = col1 - col0 + 1;
    const int psize = prows * pcols;
    const int wstride = W - pcols;                 // row jump in global plane
    const float inv_pcols = 1.0f / (float)pcols;

    // ---- per-lane DMA source offsets (element offsets, loop-invariant) ----
    // slot e = k*64 + lane; clamped so slots psize..smax*64-1 re-fetch the
    // last element (finite). smax covers psize+1 (paired reads touch psize).
    const int smax = (psize >> 6) + 1;             // 1..14, block-uniform
    int gsrc[SMAXN];
#pragma unroll
    for (int k = 0; k < SMAXN; ++k) {
        if (k < smax) {
            const int e = k * 64 + lane;
            const int ec = min(e, psize - 1);
            const int rr = (int)floorf(((float)ec + 0.5f) * inv_pcols);
            gsrc[k] = ec + rr * wstride;
        } else {
            gsrc[k] = 0;
        }
    }

    // ---- per-lane bin: 4 samples -> 8 horizontal pairs (offs, w0, w1) ----
    // pair value = w0*p[off] + w1*p[off+1]; xh==xl edge -> lx=0 -> w1=0.
    int   offs[8];
    float wt0[8], wt1[8];
    {
        const int bb = active ? bin : 0;
        const int ph = bb / 7;
        const int pw = bb - ph * 7;
#pragma unroll
        for (int g = 0; g < 4; ++g) {
            const int iy = g >> 1, ix = g & 1;
            const float gy = (float)ph + ((float)iy + 0.5f) * 0.5f;
            const float gx = (float)pw + ((float)ix + 0.5f) * 0.5f;
            const float y = y1 + gy * bin_h;
            const float x = x1 + gx * bin_w;
            const bool valid = (y >= -1.0f) && (y <= (float)H) &&
                               (x >= -1.0f) && (x <= (float)W);
            const float yc = fminf(fmaxf(y, 0.0f), (float)(H - 1));
            const float xc = fminf(fmaxf(x, 0.0f), (float)(W - 1));
            const int yl = (int)floorf(yc);
            const int xl = (int)floorf(xc);
            const int yh = min(yl + 1, H - 1);
            const float ly = yc - (float)yl;
            const float lx = xc - (float)xl;
            const float hy = 1.0f - ly, hx = 1.0f - lx;
            const float m = valid ? 0.25f : 0.0f;
            const int cx0 = xl - col0;
            offs[g * 2 + 0] = (yl - row0) * pcols + cx0;   // top-row pair
            wt0[g * 2 + 0] = hy * hx * m;
            wt1[g * 2 + 0] = hy * lx * m;
            offs[g * 2 + 1] = (yh - row0) * pcols + cx0;   // bottom-row pair
            wt0[g * 2 + 1] = ly * hx * m;
            wt1[g * 2 + 1] = ly * lx * m;
        }
    }

    // ---- wave-private double-buffered slabs; NO barriers anywhere ----
    __shared__ float slabs[4][2][SLABN];  // 28672 B -> 5 blocks/CU

    const int cw = chunk * 32 + w * 8;    // this wave's first channel
    const float* __restrict__ fch =
        feat + (size_t)(b * C + cw) * HW + (row0 * W + col0);
    float* __restrict__ op =
        out + ((size_t)r * C + cw) * PHW + bin;

    // DMA: dest = wave-uniform base + lane*4 (slot k*64+lane <- gsrc[k]).
#define STAGE(BUF, CP)                                                     \
    do {                                                                   \
        const float* gp = fch + (size_t)(CP) * HW;                         \
        _Pragma("unroll")                                                  \
        for (int k = 0; k < SMAXN; ++k) {                                  \
            if (k < smax) {                                                \
                __builtin_amdgcn_global_load_lds(                          \
                    (const __attribute__((address_space(1))) void*)        \
                        (gp + gsrc[k]),                                    \
                    (__attribute__((address_space(3))) void*)              \
                        (&slabs[w][BUF][k * 64]),                          \
                    4, 0, 0);                                              \
            }                                                              \
        }                                                                  \
    } while (0)

    STAGE(0, 0);
#pragma unroll
    for (int cp = 0; cp < 8; ++cp) {
        // Wave-local wait: slab cp&1's DMA was issued one full pass ago.
        asm volatile("s_waitcnt vmcnt(0)" ::: "memory");
        __builtin_amdgcn_sched_barrier(0);
        if (cp < 7) STAGE((cp + 1) & 1, cp + 1);   // prefetch next channel
        if (active) {
            const float* __restrict__ p = &slabs[w][cp & 1][0];
            float acc = 0.0f;
#pragma unroll
            for (int j = 0; j < 8; ++j) {
                const float a0 = p[offs[j]];       // adjacent pair ->
                const float a1 = p[offs[j] + 1];   //   ds_read2_b32
                acc = fmaf(wt0[j], a0, acc);
                acc = fmaf(wt1[j], a1, acc);
            }
            op[(size_t)cp * PHW] = acc;            // 49 consecutive dwords
        }
    }
#undef STAGE
}

extern "C" void kernel_launch(void* const* d_in, const int* in_sizes, int n_in,
                              void* d_out, int out_size, void* d_ws, size_t ws_size,
                              hipStream_t stream) {
    const float* f0 = (const float*)d_in[0];
    const float* f1 = (const float*)d_in[1];
    const float* f2 = (const float*)d_in[2];
    const float* f3 = (const float*)d_in[3];
    const float* boxes = (const float*)d_in[4];
    float* out = (float*)d_out;

    const int R = in_sizes[4] / 4;   // 512 rois
    dim3 grid(R, NCHUNK);
    msroi_kernel<<<grid, 256, 0, stream>>>(f0, f1, f2, f3, boxes, out);
}